// Round 1
// baseline (169.085 us; speedup 1.0000x reference)
//
#include <hip/hip_runtime.h>

// RoI bilinear pooling.
// img : (1, H=200, W=200, C=256) fp32, NHWC  -> channel vectors contiguous (1 KiB)
// rois: (1, N=2000, 4) fp32 (integer-valued x,y,w,h)
// out : (1, N, ps, ps, C) fp32
//
// Fast path (ps==7, C==256): one BLOCK per roi (7 waves = 448 threads), one
// WAVE per pooled row (roi,py). Each lane owns one float4 of the 256-channel
// vector. The px loop is fully unrolled: all 28 corner loads (4 per px) are
// issued before any blend -> deep MLP per wave; roi decode / y-math / int
// divides are amortized over 7 cells (divides are eliminated entirely).
// Whole-roi reads funnel through one CU's L1 so duplicate corner fetches
// dedup. Output is written with non-temporal stores (write-once, 98 MB) so it
// doesn't evict the 41 MB image from L2/L3.

typedef float vfloat4 __attribute__((ext_vector_type(4)));

template <int PS>
__global__ __launch_bounds__(PS * 64) void RoIPool_rows_kernel(
    const float* __restrict__ feat,   // H*W*C
    const float* __restrict__ rois,   // N*4
    float*       __restrict__ out,    // N*PS*PS*C
    int H, int W)
{
    constexpr int C4 = 64;            // C = 256 floats = 64 float4; lane==chunk
    const int roi  = blockIdx.x;
    const int py   = threadIdx.x >> 6;   // wave id == pooled row
    const int lane = threadIdx.x & 63;

    // uniform index -> compiler emits s_load_dwordx4
    const float4 r = reinterpret_cast<const float4*>(rois)[roi];
    const int x = (int)r.x;   // astype(int32) == trunc; values are >= 0
    const int y = (int)r.y;
    const int w = (int)r.z;
    const int h = (int)r.w;

    // match reference fp32 math exactly
    const float sy = (float)h / (float)PS;
    const float sx = (float)w / (float)PS;

    const float src_y = (float)py * sy;
    const int   y0    = (int)floorf(src_y);
    const float wy    = src_y - (float)y0;
    const float omwy  = 1.0f - wy;
    const int gy0 = min(max(y + min(max(y0,     0), h - 1), 0), H - 1);
    const int gy1 = min(max(y + min(max(y0 + 1, 0), h - 1), 0), H - 1);

    const float4* __restrict__ f4 = reinterpret_cast<const float4*>(feat);

    const int rb0 = gy0 * W * C4 + lane;   // fits int: 200*200*64 = 2.56M
    const int rb1 = gy1 * W * C4 + lane;

    // compile-time-indexed (fully unrolled) -> stays in VGPRs, not scratch
    float4 v00[PS], v01[PS], v10[PS], v11[PS];
    float  wxa[PS];

#pragma unroll
    for (int px = 0; px < PS; ++px) {
        const float src_x = (float)px * sx;
        const int   x0    = (int)floorf(src_x);
        wxa[px] = src_x - (float)x0;
        const int gx0 = min(max(x + min(max(x0,     0), w - 1), 0), W - 1);
        const int gx1 = min(max(x + min(max(x0 + 1, 0), w - 1), 0), W - 1);
        v00[px] = f4[rb0 + gx0 * C4];
        v01[px] = f4[rb0 + gx1 * C4];
        v10[px] = f4[rb1 + gx0 * C4];
        v11[px] = f4[rb1 + gx1 * C4];
    }

    vfloat4* __restrict__ o4 = reinterpret_cast<vfloat4*>(out);
    const int ob = (roi * (PS * PS) + py * PS) * C4 + lane;

#pragma unroll
    for (int px = 0; px < PS; ++px) {
        const float wx   = wxa[px];
        const float omwx = 1.0f - wx;
        vfloat4 o;
        o.x = (v00[px].x * omwx + v01[px].x * wx) * omwy + (v10[px].x * omwx + v11[px].x * wx) * wy;
        o.y = (v00[px].y * omwx + v01[px].y * wx) * omwy + (v10[px].y * omwx + v11[px].y * wx) * wy;
        o.z = (v00[px].z * omwx + v01[px].z * wx) * omwy + (v10[px].z * omwx + v11[px].z * wx) * wy;
        o.w = (v00[px].w * omwx + v01[px].w * wx) * omwy + (v10[px].w * omwx + v11[px].w * wx) * wy;
        __builtin_nontemporal_store(o, o4 + ob + px * C4);
    }
}

// ---- fallback: previous verified per-cell kernel (any ps / C multiple of 4)

__global__ __launch_bounds__(256) void RoIPool_53575422050620_kernel(
    const float* __restrict__ feat,   // H*W*C
    const float* __restrict__ rois,   // N*4
    const int*   __restrict__ psp,    // pool_size scalar
    float*       __restrict__ out,    // n_cells*C
    int n_cells, int H, int W, int C)
{
    const int ps   = psp[0];
    const int cell = blockIdx.x * 4 + (threadIdx.x >> 6);
    if (cell >= n_cells) return;
    const int lane = threadIdx.x & 63;

    const int pp  = ps * ps;
    const int roi = cell / pp;
    const int rem = cell - roi * pp;
    const int py  = rem / ps;
    const int px  = rem - py * ps;

    const float4 r = reinterpret_cast<const float4*>(rois)[roi];
    const int x = (int)r.x;
    const int y = (int)r.y;
    const int w = (int)r.z;
    const int h = (int)r.w;

    const float sy    = (float)h / (float)ps;
    const float sx    = (float)w / (float)ps;
    const float src_y = (float)py * sy;
    const float src_x = (float)px * sx;
    const int y0 = (int)floorf(src_y);
    const int x0 = (int)floorf(src_x);
    const float wy = src_y - (float)y0;
    const float wx = src_x - (float)x0;

    const int gy0 = min(max(y + min(max(y0,     0), h - 1), 0), H - 1);
    const int gy1 = min(max(y + min(max(y0 + 1, 0), h - 1), 0), H - 1);
    const int gx0 = min(max(x + min(max(x0,     0), w - 1), 0), W - 1);
    const int gx1 = min(max(x + min(max(x0 + 1, 0), w - 1), 0), W - 1);

    const int C4 = C >> 2;
    const float4* __restrict__ f4 = reinterpret_cast<const float4*>(feat);
    float4* __restrict__ o4 = reinterpret_cast<float4*>(out);

    const size_t b00 = (size_t)(gy0 * W + gx0) * C4;
    const size_t b01 = (size_t)(gy0 * W + gx1) * C4;
    const size_t b10 = (size_t)(gy1 * W + gx0) * C4;
    const size_t b11 = (size_t)(gy1 * W + gx1) * C4;
    const size_t ob  = (size_t)cell * C4;

    const float omwx = 1.0f - wx;
    const float omwy = 1.0f - wy;

    for (int cv = lane; cv < C4; cv += 64) {
        const float4 v00 = f4[b00 + cv];
        const float4 v01 = f4[b01 + cv];
        const float4 v10 = f4[b10 + cv];
        const float4 v11 = f4[b11 + cv];
        float4 o;
        o.x = (v00.x * omwx + v01.x * wx) * omwy + (v10.x * omwx + v11.x * wx) * wy;
        o.y = (v00.y * omwx + v01.y * wx) * omwy + (v10.y * omwx + v11.y * wx) * wy;
        o.z = (v00.z * omwx + v01.z * wx) * omwy + (v10.z * omwx + v11.z * wx) * wy;
        o.w = (v00.w * omwx + v01.w * wx) * omwy + (v10.w * omwx + v11.w * wx) * wy;
        o4[ob + cv] = o;
    }
}

extern "C" void kernel_launch(void* const* d_in, const int* in_sizes, int n_in,
                              void* d_out, int out_size, void* d_ws, size_t ws_size,
                              hipStream_t stream) {
    const float* img  = (const float*)d_in[0];
    const float* rois = (const float*)d_in[1];
    const int*   psp  = (const int*)d_in[2];
    float*       out  = (float*)d_out;

    const int H = 200, W = 200, C = 256;
    const int n_cells = out_size / C;           // N * ps * ps
    const int N  = in_sizes[1] / 4;             // rois rows
    const int pp = (N > 0) ? (n_cells / N) : 0; // ps*ps
    int ps = 1;
    while (ps * ps < pp) ++ps;

    if (N > 0 && pp == 49 && ps * ps == pp && ps * ps * N == n_cells && C == 256) {
        // fast path: block per roi, wave per pooled row
        RoIPool_rows_kernel<7><<<N, 7 * 64, 0, stream>>>(img, rois, out, H, W);
    } else {
        const int blocks = (n_cells + 3) / 4;   // 4 cells (waves) per block
        RoIPool_53575422050620_kernel<<<blocks, 256, 0, stream>>>(
            img, rois, psp, out, n_cells, H, W, C);
    }
}